// Round 13
// baseline (101.621 us; speedup 1.0000x reference)
//
#include <hip/hip_runtime.h>
#include <math.h>

// ---------------------------------------------------------------------------
// NFFT forward (type-2): f_hat (B,C,256,256 complex) -> samples at M points.
// 3 dispatches. Workspace layout (256 MB available; we use 6 MB):
//   Grows (bf16x4): [b][256][512] uint2  @ 0      (compact nonzero rows)
//   Gcols (bf16x4): [b][512][512] uint2  @ 2 MB   (full col-FFT'd grid)
// rows: channel-merged deconvolve/pad/fftshift + row FFT, bf16x4 out.
// cols: bf16 in, fp32 FFT in LDS, bf16x4 out.
// gather: 4-lane quads per point, DPP quad_perm for broadcast + reduction
//   (R11 post-mortem: the 8-lane __shfl gather spent ~9us on the DS pipe;
//   DPP moves all cross-lane work to VALU and halves wave count).
//   R12 fix: dpp_ctrl must be a template parameter (ICE at the builtin call).
// Shift algebra: ifftshift(FFT(fftshift(p)))[(ind+256)%512] == FFT(fftshift(p))[ind&511].
// Output PLANAR: real plane (B,C,M) then imag plane.
// R4: no forced __launch_bounds__ minima. R5: coalesce scattered gathers.
// R8: never cooperative grid.sync. R10: ~46us/replay is harness poison+restore
// (untouchable floor).
// ---------------------------------------------------------------------------

#define NGRID 512
#define NSMALL 256
#define MW 4
#define BB 2
#define CC 2
#define MPTS 200000
#define PLANE (BB * CC * MPTS)   // imag-plane offset in floats
#define LPAD4 513                // LDS pitch in float4 (breaks pow2 banking)
#define GROWS_B 131072           // uint2 per b-image in Grows (256*512)
#define GCOLS_OFF 262144         // uint2 offset of Gcols region (2 MB)
#define GCOLS_B 262144           // uint2 per b-image in Gcols (512*512)

// I0(z) asymptotic series, valid z > 8 (our z in [17.7, 18.9])
__device__ __forceinline__ float nfft29781_i0_large(float z) {
    float inv = 1.0f / z;
    float p = 1.0f + inv * (0.125f + inv * (0.0703125f
              + inv * (0.0732421875f + inv * 0.112152099609375f)));
    return expf(z) * rsqrtf(2.0f * (float)M_PI * z) * p;
}

__device__ __forceinline__ int nfft29781_brev9(int v) {
    return (int)(__brev((unsigned)v) >> 23);
}

__device__ __forceinline__ unsigned nfft29781_bf16pack(float a, float b) {
    unsigned ua = __float_as_uint(a);
    ua += 0x7FFFu + ((ua >> 16) & 1u);           // RNE
    unsigned ub = __float_as_uint(b);
    ub += 0x7FFFu + ((ub >> 16) & 1u);
    return (ua >> 16) | (ub & 0xFFFF0000u);
}

__device__ __forceinline__ float4 nfft29781_unpk(uint2 g) {
    return make_float4(__uint_as_float(g.x << 16),
                       __uint_as_float(g.x & 0xFFFF0000u),
                       __uint_as_float(g.y << 16),
                       __uint_as_float(g.y & 0xFFFF0000u));
}

// 512-pt radix-2 DIT FFT on complex PAIRS (float4 = two complexes), in LDS.
__device__ __forceinline__ void nfft29781_fft512_c2(float4* s, int tid) {
    #pragma unroll
    for (int st = 0; st < 9; ++st) {
        int half = 1 << st;
        int pos = tid & (half - 1);
        int i0 = ((tid >> st) << (st + 1)) + pos;
        int i1 = i0 + half;
        float ang = -(float)M_PI * (float)pos / (float)half;
        float sn, cs;
        __sincosf(ang, &sn, &cs);
        float4 a = s[i0];
        float4 b = s[i1];
        float4 tw;
        tw.x = b.x * cs - b.y * sn;  tw.y = b.x * sn + b.y * cs;
        tw.z = b.z * cs - b.w * sn;  tw.w = b.z * sn + b.w * cs;
        s[i0] = make_float4(a.x + tw.x, a.y + tw.y, a.z + tw.z, a.w + tw.w);
        s[i1] = make_float4(a.x - tw.x, a.y - tw.y, a.z - tw.z, a.w - tw.w);
        __syncthreads();
    }
}

// ---------------------------------------------------------------------------
// Rows (R11-proven): one block per (b, a1); both channels in a float4.
// Output packed bf16 into compact Grows[b][q][col], q = a1 ^ 128.
// ---------------------------------------------------------------------------
__global__ __launch_bounds__(256) void nfft29781_rows3(const float* __restrict__ fr,
                                                       const float* __restrict__ fi,
                                                       uint2* __restrict__ Grows) {
    __shared__ float4 s[NGRID];
    int tid = threadIdx.x;
    int b   = blockIdx.x >> 8;
    int a1  = blockIdx.x & 255;

    const float bcon  = 1.5f * (float)M_PI;
    const float scale = 2.0f * (float)M_PI / (float)NGRID;
    float k1 = (float)(a1 - 128) * scale;
    float p1 = nfft29781_i0_large((float)MW * sqrtf(bcon * bcon - k1 * k1));

    int a2 = tid ^ 128;
    float k2 = (float)(a2 - 128) * scale;
    float p2 = nfft29781_i0_large((float)MW * sqrtf(bcon * bcon - k2 * k2));
    float invp = 1.0f / (p1 * p2);

    size_t s0 = ((size_t)(b * CC + 0) * NSMALL + a1) * NSMALL + a2;
    size_t s1 = ((size_t)(b * CC + 1) * NSMALL + a1) * NSMALL + a2;
    float4 v = make_float4(fr[s0] * invp, fi[s0] * invp,
                           fr[s1] * invp, fi[s1] * invp);

    int j2v = (tid < 128) ? tid : tid + 256;        // nonzero staged col
    int j2z = (tid < 128) ? tid + 256 : tid;        // zero staged col
    s[nfft29781_brev9(j2v)] = v;
    s[nfft29781_brev9(j2z)] = make_float4(0.0f, 0.0f, 0.0f, 0.0f);
    __syncthreads();

    nfft29781_fft512_c2(s, tid);

    int q = a1 ^ 128;                               // compact row index
    uint2* Gr = Grows + ((size_t)b * NSMALL + q) * NGRID;
    float4 v0 = s[tid], v1 = s[tid + 256];
    uint2 pk0, pk1;
    pk0.x = nfft29781_bf16pack(v0.x, v0.y);  pk0.y = nfft29781_bf16pack(v0.z, v0.w);
    pk1.x = nfft29781_bf16pack(v1.x, v1.y);  pk1.y = nfft29781_bf16pack(v1.z, v1.w);
    Gr[tid]       = pk0;
    Gr[tid + 256] = pk1;
}

// ---------------------------------------------------------------------------
// Cols (R11-proven): one block per (b, 4-col group); bf16 in/out, fp32 FFT.
// ---------------------------------------------------------------------------
__global__ __launch_bounds__(256) void nfft29781_cols3(const uint2* __restrict__ Grows,
                                                       uint2* __restrict__ Gcols) {
    __shared__ float4 s[4 * LPAD4];                 // 32.8 KB
    int tid  = threadIdx.x;
    int b    = blockIdx.x >> 7;
    int col0 = (blockIdx.x & 127) << 2;
    const uint2* Gr = Grows + (size_t)b * GROWS_B;

    #pragma unroll
    for (int it = 0; it < 4; ++it) {
        int e  = it * 256 + tid;                    // 0..1023
        int cp = e & 3;
        int q  = e >> 2;                            // 0..255 compact row
        int r  = (q < 128) ? q : q + 256;           // staged row
        s[cp * LPAD4 + nfft29781_brev9(r)] =
            nfft29781_unpk(Gr[(size_t)q * NGRID + col0 + cp]);
    }
    #pragma unroll
    for (int it = 0; it < 4; ++it) {                // zero the middle rows
        int e  = it * 256 + tid;
        int cp = e & 3;
        int q  = e >> 2;
        s[cp * LPAD4 + nfft29781_brev9(q + 128)] = make_float4(0.0f, 0.0f, 0.0f, 0.0f);
    }
    __syncthreads();

    int c = tid & 3;
    int w = tid >> 2;                               // 0..63
    float4* sc = s + c * LPAD4;
    for (int st = 0; st < 9; ++st) {
        int half = 1 << st;
        #pragma unroll
        for (int k = 0; k < 4; ++k) {
            int bf  = w + (k << 6);                 // 0..255
            int pos = bf & (half - 1);
            int i0  = ((bf >> st) << (st + 1)) + pos;
            int i1  = i0 + half;
            float ang = -(float)M_PI * (float)pos / (float)half;
            float sn, cs;
            __sincosf(ang, &sn, &cs);
            float4 a = sc[i0];
            float4 bb = sc[i1];
            float4 tw;
            tw.x = bb.x * cs - bb.y * sn;  tw.y = bb.x * sn + bb.y * cs;
            tw.z = bb.z * cs - bb.w * sn;  tw.w = bb.z * sn + bb.w * cs;
            sc[i0] = make_float4(a.x + tw.x, a.y + tw.y, a.z + tw.z, a.w + tw.w);
            sc[i1] = make_float4(a.x - tw.x, a.y - tw.y, a.z - tw.z, a.w - tw.w);
        }
        __syncthreads();
    }

    uint2* Gc = Gcols + (size_t)b * GCOLS_B;
    #pragma unroll
    for (int it = 0; it < 8; ++it) {
        int e  = it * 256 + tid;                    // 0..2047
        int cp = e & 3;
        int r  = e >> 2;                            // 0..511
        float4 v = s[cp * LPAD4 + r];
        uint2 pk;
        pk.x = nfft29781_bf16pack(v.x, v.y);        // ch0 re|im
        pk.y = nfft29781_bf16pack(v.z, v.w);        // ch1 re|im
        Gc[(size_t)r * NGRID + col0 + cp] = pk;
    }
}

// ---------------------------------------------------------------------------
// DPP helpers — ctrl is a TEMPLATE parameter so the builtin sees an ICE
// (R12 compile failure: runtime arg rejected even after inlining).
// ---------------------------------------------------------------------------
template<int CTRL>
__device__ __forceinline__ float nfft29781_dpp(float v) {
    return __uint_as_float((unsigned)__builtin_amdgcn_mov_dpp(
        (int)__float_as_uint(v), CTRL, 0xf, 0xf, true));
}

template<int I>
__device__ __forceinline__ float nfft29781_bcast_w0(float w0lo, float w0hi) {
    constexpr int ctrl = (I >> 1) * 0x55;           // quad_perm [q,q,q,q]
    float src = (I & 1) ? w0hi : w0lo;
    return nfft29781_dpp<ctrl>(src);
}

__device__ __forceinline__ float nfft29781_qsum(float v) {
    v += nfft29781_dpp<0xB1>(v);                    // quad_perm [1,0,3,2]
    v += nfft29781_dpp<0x4E>(v);                    // quad_perm [2,3,0,1]
    return v;
}

// Kaiser-Bessel weight for integer tap index (bit-matches ceil(x*n)-m seq).
__device__ __forceinline__ float nfft29781_w(int tap, float d) {
    const float bw = 1.5f * (float)M_PI;
    const float invpi = 1.0f / (float)M_PI;
    float nk = (float)(MW - tap) - d;
    float tt = (float)(MW * MW) - nk * nk;
    float wv = 0.0f;
    if (tt > 0.0f) {
        float a = sqrtf(tt);
        float e = expf(bw * a);
        wv = (e - 1.0f / e) * 0.5f * invpi / a;
    }
    return wv;
}

template<int I>
__device__ __forceinline__ void nfft29781_step(const uint2* __restrict__ Gi,
                                               int base0, int cix0, int cix1,
                                               float w0lo, float w0hi,
                                               float* a0, float* a1) {
    float w0i = nfft29781_bcast_w0<I>(w0lo, w0hi);  // row-I weight, via DPP
    int row = (base0 + I) & (NGRID - 1);
    const uint2* rp = Gi + ((size_t)row << 9);
    float4 u0 = nfft29781_unpk(rp[cix0]);
    float4 u1 = nfft29781_unpk(rp[cix1]);
    a0[0] += w0i * u0.x;  a0[1] += w0i * u0.y;
    a0[2] += w0i * u0.z;  a0[3] += w0i * u0.w;
    a1[0] += w0i * u1.x;  a1[1] += w0i * u1.y;
    a1[2] += w0i * u1.z;  a1[3] += w0i * u1.w;
}

// ---------------------------------------------------------------------------
// Gather: 4-lane quad per point. Lane j owns column-taps {2j, 2j+1} (quad
// covers the contiguous 64B row segment; two 8B loads per lane per row-tap,
// each wrap-masked). Weights per lane: w0/w1 for its 2 taps. Cross-lane:
// DPP only (no LDS). Lane 0 of the quad writes planar out.
// ---------------------------------------------------------------------------
__global__ __launch_bounds__(256) void nfft29781_gather_dpp(const float* __restrict__ x,
                                                            const uint2* __restrict__ Gcols,
                                                            float* __restrict__ out,
                                                            int out_elems) {
    int t  = blockIdx.x * blockDim.x + threadIdx.x;
    int j  = t & 3;                  // my quad lane
    int pp = t >> 2;                 // (b, point) id
    if (pp >= BB * MPTS) return;     // exact grid: never taken (quads uniform)
    int b  = (pp >= MPTS) ? 1 : 0;
    int pt = pp - b * MPTS;

    float2 xv = ((const float2*)x)[pp];             // quad-uniform broadcast
    float u0 = xv.x * (float)NGRID;
    float u1 = xv.y * (float)NGRID;
    float c0 = ceilf(u0), c1 = ceilf(u1);
    int base0 = (int)c0 - MW;
    int base1 = (int)c1 - MW;
    float d0 = c0 - u0, d1 = c1 - u1;

    int t0 = 2 * j, t1 = 2 * j + 1;                 // my column taps
    float w0lo = nfft29781_w(t0, d0);               // my row weights (slots)
    float w0hi = nfft29781_w(t1, d0);
    float w1lo = nfft29781_w(t0, d1);               // my column weights
    float w1hi = nfft29781_w(t1, d1);

    const uint2* Gi = Gcols + (size_t)b * GCOLS_B;
    int cix0 = (base1 + t0) & (NGRID - 1);
    int cix1 = (base1 + t1) & (NGRID - 1);

    float a0[4] = {0.f, 0.f, 0.f, 0.f};             // tap 2j   : ch0re,ch0im,ch1re,ch1im
    float a1[4] = {0.f, 0.f, 0.f, 0.f};             // tap 2j+1
    nfft29781_step<0>(Gi, base0, cix0, cix1, w0lo, w0hi, a0, a1);
    nfft29781_step<1>(Gi, base0, cix0, cix1, w0lo, w0hi, a0, a1);
    nfft29781_step<2>(Gi, base0, cix0, cix1, w0lo, w0hi, a0, a1);
    nfft29781_step<3>(Gi, base0, cix0, cix1, w0lo, w0hi, a0, a1);
    nfft29781_step<4>(Gi, base0, cix0, cix1, w0lo, w0hi, a0, a1);
    nfft29781_step<5>(Gi, base0, cix0, cix1, w0lo, w0hi, a0, a1);
    nfft29781_step<6>(Gi, base0, cix0, cix1, w0lo, w0hi, a0, a1);
    nfft29781_step<7>(Gi, base0, cix0, cix1, w0lo, w0hi, a0, a1);

    float r0 = w1lo * a0[0] + w1hi * a1[0];         // ch0 re
    float r1 = w1lo * a0[1] + w1hi * a1[1];         // ch0 im
    float r2 = w1lo * a0[2] + w1hi * a1[2];         // ch1 re
    float r3 = w1lo * a0[3] + w1hi * a1[3];         // ch1 im
    r0 = nfft29781_qsum(r0);
    r1 = nfft29781_qsum(r1);
    r2 = nfft29781_qsum(r2);
    r3 = nfft29781_qsum(r3);

    if (j == 0) {
        size_t o0 = (size_t)(b * CC) * MPTS + pt;   // channel 0
        size_t o1 = o0 + MPTS;                      // channel 1
        if (o0 < (size_t)out_elems)         out[o0]         = r0;
        if (PLANE + o0 < (size_t)out_elems) out[PLANE + o0] = r1;
        if (o1 < (size_t)out_elems)         out[o1]         = r2;
        if (PLANE + o1 < (size_t)out_elems) out[PLANE + o1] = r3;
    }
}

extern "C" void kernel_launch(void* const* d_in, const int* in_sizes, int n_in,
                              void* d_out, int out_size, void* d_ws, size_t ws_size,
                              hipStream_t stream) {
    (void)in_sizes; (void)n_in;
    const float* x  = (const float*)d_in[0];
    const float* fr = (const float*)d_in[1];
    const float* fi = (const float*)d_in[2];
    float* out  = (float*)d_out;
    uint2* Grows = (uint2*)d_ws;                 // 2 MB
    uint2* Gcols = (uint2*)d_ws + GCOLS_OFF;     // 4 MB @ +2 MB

    if (ws_size < (size_t)8 * 1024 * 1024) return;   // diagnostic no-op

    nfft29781_rows3<<<BB * NSMALL, 256, 0, stream>>>(fr, fi, Grows);
    nfft29781_cols3<<<BB * (NGRID / 4), 256, 0, stream>>>(Grows, Gcols);
    int gthreads = BB * MPTS * 4;                // 4-lane quad per point
    nfft29781_gather_dpp<<<(gthreads + 255) / 256, 256, 0, stream>>>(
        x, Gcols, out, out_size);
}

// Round 14
// 99.294 us; speedup vs baseline: 1.0234x; 1.0234x over previous
//
#include <hip/hip_runtime.h>
#include <math.h>

// ---------------------------------------------------------------------------
// NFFT forward (type-2): f_hat (B,C,256,256 complex) -> samples at M points.
// 3 dispatches. Workspace layout (uses 6 MB of d_ws):
//   Grows (bf16x4): [b][256][512] uint2  @ 0      (compact nonzero rows)
//   Gcols (bf16x4): [b][512][512] uint2  @ 2 MB   (full col-FFT'd grid)
// rows: channel-merged deconvolve/pad/fftshift + row FFT, bf16x4 out.
// cols: bf16 in, fp32 FFT in LDS, bf16x4 out.
// gather: R10-proven 8-lane-per-point layout (one 8B load/lane/row-tap =
//   one TA line-lookup pass per 64B segment — R13's quad-DPP layout doubled
//   lookups and regressed). float2 accumulators to coax v_pk_fma_f32.
// Shift algebra: ifftshift(FFT(fftshift(p)))[(ind+256)%512] == FFT(fftshift(p))[ind&511].
// Output PLANAR: real plane (B,C,M) then imag plane.
// Session lessons: R4 no forced __launch_bounds__ minima (spill=dead kernel);
// R5 coalesce scattered gathers; R8 never cooperative grid.sync (8-XCD L2
// flush catastrophe); R10 ~44us/replay is harness ws-poison (hard floor);
// R11/R13 gather is TA-line + VALU bound, not latency/DS bound.
// ---------------------------------------------------------------------------

#define NGRID 512
#define NSMALL 256
#define MW 4
#define BB 2
#define CC 2
#define MPTS 200000
#define PLANE (BB * CC * MPTS)   // imag-plane offset in floats
#define LPAD4 513                // LDS pitch in float4 (breaks pow2 banking)
#define GROWS_B 131072           // uint2 per b-image in Grows (256*512)
#define GCOLS_OFF 262144         // uint2 offset of Gcols region (2 MB)
#define GCOLS_B 262144           // uint2 per b-image in Gcols (512*512)

// I0(z) asymptotic series, valid z > 8 (our z in [17.7, 18.9])
__device__ __forceinline__ float nfft29781_i0_large(float z) {
    float inv = 1.0f / z;
    float p = 1.0f + inv * (0.125f + inv * (0.0703125f
              + inv * (0.0732421875f + inv * 0.112152099609375f)));
    return expf(z) * rsqrtf(2.0f * (float)M_PI * z) * p;
}

__device__ __forceinline__ int nfft29781_brev9(int v) {
    return (int)(__brev((unsigned)v) >> 23);
}

__device__ __forceinline__ unsigned nfft29781_bf16pack(float a, float b) {
    unsigned ua = __float_as_uint(a);
    ua += 0x7FFFu + ((ua >> 16) & 1u);           // RNE
    unsigned ub = __float_as_uint(b);
    ub += 0x7FFFu + ((ub >> 16) & 1u);
    return (ua >> 16) | (ub & 0xFFFF0000u);
}

__device__ __forceinline__ float4 nfft29781_unpk(uint2 g) {
    return make_float4(__uint_as_float(g.x << 16),
                       __uint_as_float(g.x & 0xFFFF0000u),
                       __uint_as_float(g.y << 16),
                       __uint_as_float(g.y & 0xFFFF0000u));
}

// 512-pt radix-2 DIT FFT on complex PAIRS (float4 = two complexes), in LDS.
__device__ __forceinline__ void nfft29781_fft512_c2(float4* s, int tid) {
    #pragma unroll
    for (int st = 0; st < 9; ++st) {
        int half = 1 << st;
        int pos = tid & (half - 1);
        int i0 = ((tid >> st) << (st + 1)) + pos;
        int i1 = i0 + half;
        float ang = -(float)M_PI * (float)pos / (float)half;
        float sn, cs;
        __sincosf(ang, &sn, &cs);
        float4 a = s[i0];
        float4 b = s[i1];
        float4 tw;
        tw.x = b.x * cs - b.y * sn;  tw.y = b.x * sn + b.y * cs;
        tw.z = b.z * cs - b.w * sn;  tw.w = b.z * sn + b.w * cs;
        s[i0] = make_float4(a.x + tw.x, a.y + tw.y, a.z + tw.z, a.w + tw.w);
        s[i1] = make_float4(a.x - tw.x, a.y - tw.y, a.z - tw.z, a.w - tw.w);
        __syncthreads();
    }
}

// ---------------------------------------------------------------------------
// Rows (R11-proven): one block per (b, a1); both channels in a float4.
// Output packed bf16 into compact Grows[b][q][col], q = a1 ^ 128.
// ---------------------------------------------------------------------------
__global__ __launch_bounds__(256) void nfft29781_rows3(const float* __restrict__ fr,
                                                       const float* __restrict__ fi,
                                                       uint2* __restrict__ Grows) {
    __shared__ float4 s[NGRID];
    int tid = threadIdx.x;
    int b   = blockIdx.x >> 8;
    int a1  = blockIdx.x & 255;

    const float bcon  = 1.5f * (float)M_PI;
    const float scale = 2.0f * (float)M_PI / (float)NGRID;
    float k1 = (float)(a1 - 128) * scale;
    float p1 = nfft29781_i0_large((float)MW * sqrtf(bcon * bcon - k1 * k1));

    int a2 = tid ^ 128;
    float k2 = (float)(a2 - 128) * scale;
    float p2 = nfft29781_i0_large((float)MW * sqrtf(bcon * bcon - k2 * k2));
    float invp = 1.0f / (p1 * p2);

    size_t s0 = ((size_t)(b * CC + 0) * NSMALL + a1) * NSMALL + a2;
    size_t s1 = ((size_t)(b * CC + 1) * NSMALL + a1) * NSMALL + a2;
    float4 v = make_float4(fr[s0] * invp, fi[s0] * invp,
                           fr[s1] * invp, fi[s1] * invp);

    int j2v = (tid < 128) ? tid : tid + 256;        // nonzero staged col
    int j2z = (tid < 128) ? tid + 256 : tid;        // zero staged col
    s[nfft29781_brev9(j2v)] = v;
    s[nfft29781_brev9(j2z)] = make_float4(0.0f, 0.0f, 0.0f, 0.0f);
    __syncthreads();

    nfft29781_fft512_c2(s, tid);

    int q = a1 ^ 128;                               // compact row index
    uint2* Gr = Grows + ((size_t)b * NSMALL + q) * NGRID;
    float4 v0 = s[tid], v1 = s[tid + 256];
    uint2 pk0, pk1;
    pk0.x = nfft29781_bf16pack(v0.x, v0.y);  pk0.y = nfft29781_bf16pack(v0.z, v0.w);
    pk1.x = nfft29781_bf16pack(v1.x, v1.y);  pk1.y = nfft29781_bf16pack(v1.z, v1.w);
    Gr[tid]       = pk0;
    Gr[tid + 256] = pk1;
}

// ---------------------------------------------------------------------------
// Cols (R11-proven): one block per (b, 4-col group); bf16 in/out, fp32 FFT.
// ---------------------------------------------------------------------------
__global__ __launch_bounds__(256) void nfft29781_cols3(const uint2* __restrict__ Grows,
                                                       uint2* __restrict__ Gcols) {
    __shared__ float4 s[4 * LPAD4];                 // 32.8 KB
    int tid  = threadIdx.x;
    int b    = blockIdx.x >> 7;
    int col0 = (blockIdx.x & 127) << 2;
    const uint2* Gr = Grows + (size_t)b * GROWS_B;

    #pragma unroll
    for (int it = 0; it < 4; ++it) {
        int e  = it * 256 + tid;                    // 0..1023
        int cp = e & 3;
        int q  = e >> 2;                            // 0..255 compact row
        int r  = (q < 128) ? q : q + 256;           // staged row
        s[cp * LPAD4 + nfft29781_brev9(r)] =
            nfft29781_unpk(Gr[(size_t)q * NGRID + col0 + cp]);
    }
    #pragma unroll
    for (int it = 0; it < 4; ++it) {                // zero the middle rows
        int e  = it * 256 + tid;
        int cp = e & 3;
        int q  = e >> 2;
        s[cp * LPAD4 + nfft29781_brev9(q + 128)] = make_float4(0.0f, 0.0f, 0.0f, 0.0f);
    }
    __syncthreads();

    int c = tid & 3;
    int w = tid >> 2;                               // 0..63
    float4* sc = s + c * LPAD4;
    for (int st = 0; st < 9; ++st) {
        int half = 1 << st;
        #pragma unroll
        for (int k = 0; k < 4; ++k) {
            int bf  = w + (k << 6);                 // 0..255
            int pos = bf & (half - 1);
            int i0  = ((bf >> st) << (st + 1)) + pos;
            int i1  = i0 + half;
            float ang = -(float)M_PI * (float)pos / (float)half;
            float sn, cs;
            __sincosf(ang, &sn, &cs);
            float4 a = sc[i0];
            float4 bb = sc[i1];
            float4 tw;
            tw.x = bb.x * cs - bb.y * sn;  tw.y = bb.x * sn + bb.y * cs;
            tw.z = bb.z * cs - bb.w * sn;  tw.w = bb.z * sn + bb.w * cs;
            sc[i0] = make_float4(a.x + tw.x, a.y + tw.y, a.z + tw.z, a.w + tw.w);
            sc[i1] = make_float4(a.x - tw.x, a.y - tw.y, a.z - tw.z, a.w - tw.w);
        }
        __syncthreads();
    }

    uint2* Gc = Gcols + (size_t)b * GCOLS_B;
    #pragma unroll
    for (int it = 0; it < 8; ++it) {
        int e  = it * 256 + tid;                    // 0..2047
        int cp = e & 3;
        int r  = e >> 2;                            // 0..511
        float4 v = s[cp * LPAD4 + r];
        uint2 pk;
        pk.x = nfft29781_bf16pack(v.x, v.y);        // ch0 re|im
        pk.y = nfft29781_bf16pack(v.z, v.w);        // ch1 re|im
        Gc[(size_t)r * NGRID + col0 + cp] = pk;
    }
}

// ---------------------------------------------------------------------------
// Gather (R10 structure): 8 lanes per (b,point); lane j owns column-tap j;
// per row-tap ONE 8B load/lane (one TA pass per 64B segment). Weights once
// per group; w0[i] broadcast via __shfl; float2 accumulators (pk_fma);
// 3-stage __shfl_xor butterfly; lane 0 writes planar out.
// Weight sequence bit-matches reference ceil(x*n)-m.
// ---------------------------------------------------------------------------
__global__ __launch_bounds__(256) void nfft29781_gather_bf16(const float* __restrict__ x,
                                                             const uint2* __restrict__ Gcols,
                                                             float* __restrict__ out,
                                                             int out_elems) {
    int t  = blockIdx.x * blockDim.x + threadIdx.x;
    int j  = t & 7;                  // my column tap
    int pp = t >> 3;                 // (b, point) id — shared by 8 group lanes
    if (pp >= BB * MPTS) return;
    int b  = (pp >= MPTS) ? 1 : 0;
    int pt = pp - b * MPTS;

    float2 xv = ((const float2*)x)[pp];             // group-uniform broadcast
    float u0 = xv.x * (float)NGRID;
    float u1 = xv.y * (float)NGRID;

    float c0 = ceilf(u0), c1 = ceilf(u1);
    int base0 = (int)c0 - MW;
    int base1 = (int)c1 - MW;
    float d0 = c0 - u0, d1 = c1 - u1;

    const float bw = 1.5f * (float)M_PI;
    const float invpi = 1.0f / (float)M_PI;
    float w0m, w1m;   // my dim-0 / dim-1 tap-j weights
    {
        float nk = (float)(MW - j) - d0;
        float tt = (float)(MW * MW) - nk * nk;
        w0m = 0.0f;
        if (tt > 0.0f) { float a = sqrtf(tt); float e = expf(bw * a);
                         w0m = (e - 1.0f / e) * 0.5f * invpi / a; }
        nk = (float)(MW - j) - d1;
        tt = (float)(MW * MW) - nk * nk;
        w1m = 0.0f;
        if (tt > 0.0f) { float a = sqrtf(tt); float e = expf(bw * a);
                         w1m = (e - 1.0f / e) * 0.5f * invpi / a; }
    }

    const uint2* Gi = Gcols + (size_t)b * GCOLS_B;
    int cix = (base1 + j) & (NGRID - 1);
    int lanebase = (threadIdx.x & 63) & ~7;

    float2 acc0 = make_float2(0.0f, 0.0f);          // ch0 (re, im)
    float2 acc1 = make_float2(0.0f, 0.0f);          // ch1 (re, im)
    #pragma unroll
    for (int i = 0; i < 8; ++i) {
        float w0i = __shfl(w0m, lanebase + i, 64);  // row-i weight
        uint2 g = Gi[(size_t)((((base0 + i) & (NGRID - 1)) << 9) + cix)];
        float2 g0 = make_float2(__uint_as_float(g.x << 16),
                                __uint_as_float(g.x & 0xFFFF0000u));
        float2 g1 = make_float2(__uint_as_float(g.y << 16),
                                __uint_as_float(g.y & 0xFFFF0000u));
        acc0.x = fmaf(w0i, g0.x, acc0.x);  acc0.y = fmaf(w0i, g0.y, acc0.y);
        acc1.x = fmaf(w0i, g1.x, acc1.x);  acc1.y = fmaf(w0i, g1.y, acc1.y);
    }
    acc0.x *= w1m;  acc0.y *= w1m;  acc1.x *= w1m;  acc1.y *= w1m;

    #pragma unroll
    for (int msk = 1; msk < 8; msk <<= 1) {         // sum the 8 column taps
        acc0.x += __shfl_xor(acc0.x, msk, 64);
        acc0.y += __shfl_xor(acc0.y, msk, 64);
        acc1.x += __shfl_xor(acc1.x, msk, 64);
        acc1.y += __shfl_xor(acc1.y, msk, 64);
    }

    if (j == 0) {
        size_t o0 = (size_t)(b * CC) * MPTS + pt;   // channel 0
        size_t o1 = o0 + MPTS;                      // channel 1
        if (o0 < (size_t)out_elems)         out[o0]         = acc0.x;
        if (PLANE + o0 < (size_t)out_elems) out[PLANE + o0] = acc0.y;
        if (o1 < (size_t)out_elems)         out[o1]         = acc1.x;
        if (PLANE + o1 < (size_t)out_elems) out[PLANE + o1] = acc1.y;
    }
}

extern "C" void kernel_launch(void* const* d_in, const int* in_sizes, int n_in,
                              void* d_out, int out_size, void* d_ws, size_t ws_size,
                              hipStream_t stream) {
    (void)in_sizes; (void)n_in;
    const float* x  = (const float*)d_in[0];
    const float* fr = (const float*)d_in[1];
    const float* fi = (const float*)d_in[2];
    float* out  = (float*)d_out;
    uint2* Grows = (uint2*)d_ws;                 // 2 MB
    uint2* Gcols = (uint2*)d_ws + GCOLS_OFF;     // 4 MB @ +2 MB

    if (ws_size < (size_t)8 * 1024 * 1024) return;   // diagnostic no-op

    nfft29781_rows3<<<BB * NSMALL, 256, 0, stream>>>(fr, fi, Grows);
    nfft29781_cols3<<<BB * (NGRID / 4), 256, 0, stream>>>(Grows, Gcols);
    int gthreads = BB * MPTS * 8;                // 8 lanes per (b,point)
    nfft29781_gather_bf16<<<(gthreads + 255) / 256, 256, 0, stream>>>(
        x, Gcols, out, out_size);
}